// Round 4
// baseline (195.246 us; speedup 1.0000x reference)
//
#include <hip/hip_runtime.h>

#define HIMG 256
#define WIMG 256
#define CCH  32
#define JBOX 64
#define BIMG 8
#define HGT  8
#define LMAX 204   // max staged row-segment length: bw<=200 -> floor span <= 202, +2 slack

// One block per (b, j, h). y0/y1 are block-uniform, so the block's entire
// image footprint is 2 rows x 32 channels x <=204 contiguous columns.
// Stage it into LDS with coalesced dword loads, then take the 4 bilinear
// taps from LDS (stride 1-4 words -> <=4-way bank aliasing, ~free).
// No vector-cast loads anywhere (R3's unaligned float2 was UB -> unstable).
__global__ __launch_bounds__(256) void roi_kernel(
    const float* __restrict__ img,     // (B, C, HIMG, WIMG)
    const float* __restrict__ boxes,   // (B, J, 5)
    float* __restrict__ res,           // (B, J, C, HGT, max_w)
    float* __restrict__ mask,          // (B, J, max_w)
    int max_w)
{
    __shared__ float smem[CCH][2][LMAX];   // 52,224 B -> 3 blocks/CU

    const int blk = blockIdx.x;       // bj*8 + h
    const int h   = blk & 7;
    const int bj  = blk >> 3;         // 0..511
    const int b   = bj >> 6;          // J = 64
    const int tid = threadIdx.x;

    const float left  = boxes[bj * 5 + 0];
    const float top   = boxes[bj * 5 + 1];
    const float right = boxes[bj * 5 + 2];
    const float bot   = boxes[bj * 5 + 3];
    const float bw = right - left;
    const float bh = bot - top;

    // width = int32(bw/bh * 8) with f32 ops + truncation (matches numpy).
    const int   width  = (int)(bw / bh * 8.0f);
    const float each_w = bw / ((float)width - 1.0f);
    const float each_h = bh / 7.0f;

    // y for this h (block-uniform). Separate mul/add roundings (match numpy).
    const float y  = __fadd_rn(__fmul_rn((float)h, each_h), top);
    const int   yf = (int)floorf(y);
    const int   y0 = min(max(yf,     0), HIMG - 1);
    const int   y1 = min(max(yf + 1, 0), HIMG - 1);
    const float wy1 = (float)y1 - y;
    const float wy0 = y - (float)y0;

    // Staging column bounds (conservative cover of all x0/x1).
    const int xs = max((int)floorf(left), 0);
    const int xe = min((int)floorf(right) + 2, WIMG - 1);
    const int L  = xe - xs + 1;   // <= LMAX

    // Coalesced staging: 8 groups of 32 lanes walk the 64 (ch,row) segments.
    {
        const int g    = tid >> 5;    // 0..7
        const int lane = tid & 31;
        for (int seg = g; seg < 2 * CCH; seg += 8) {
            const int ch  = seg >> 1;
            const int r   = seg & 1;
            const int row = r ? y1 : y0;
            const float* src = img + (((size_t)b * CCH + ch) * HIMG + row) * WIMG;
            for (int off = lane; off < L; off += 32) {
                smem[ch][r][off] = src[xs + off];
            }
        }
    }

    const int  i    = tid;
    const bool have = (i < max_w);
    const bool in_w = (i < width);

    if (h == 0 && have) {
        __builtin_nontemporal_store(in_w ? 1.0f : 0.0f,
                                    &mask[(size_t)bj * max_w + i]);
    }

    // res[((bj*C + c)*HGT + h)*max_w + i]
    float* resp = res + ((size_t)bj * CCH * HGT + h) * (size_t)max_w + i;
    const size_t c_stride = (size_t)HGT * max_w;

    // Masked region: zero-fill before the barrier (doesn't touch smem).
    if (have && !in_w) {
        #pragma unroll
        for (int c = 0; c < CCH; ++c) {
            __builtin_nontemporal_store(0.0f, &resp[(size_t)c * c_stride]);
        }
    }

    __syncthreads();

    if (have && in_w) {
        const float x  = __fadd_rn(__fmul_rn((float)i, each_w), left);
        const int   xf = (int)floorf(x);
        const int   x0 = min(max(xf,     0), WIMG - 1);
        const int   x1 = min(max(xf + 1, 0), WIMG - 1);

        const float wx1 = (float)x1 - x;
        const float wx0 = x - (float)x0;
        const float wa = wx1 * wy1;
        const float wb = wx1 * wy0;
        const float wc = wx0 * wy1;
        const float wd = wx0 * wy0;

        // LDS column indices (clamp only guards against LDS OOB; never
        // bites for in-range data).
        const int lx0 = min(max(x0 - xs, 0), LMAX - 1);
        const int lx1 = min(max(x1 - xs, 0), LMAX - 1);

        #pragma unroll 8
        for (int c = 0; c < CCH; ++c) {
            const float va = smem[c][0][lx0];
            const float vc = smem[c][0][lx1];
            const float vb = smem[c][1][lx0];
            const float vd = smem[c][1][lx1];
            const float val = va * wa + vb * wb + vc * wc + vd * wd;
            __builtin_nontemporal_store(val, &resp[(size_t)c * c_stride]);
        }
    }
}

extern "C" void kernel_launch(void* const* d_in, const int* in_sizes, int n_in,
                              void* d_out, int out_size, void* d_ws, size_t ws_size,
                              hipStream_t stream) {
    const float* img   = (const float*)d_in[0];
    const float* boxes = (const float*)d_in[1];
    float* out = (float*)d_out;

    const int per_w = BIMG * JBOX * CCH * HGT + BIMG * JBOX;  // 131584
    const int max_w = out_size / per_w;

    float* res  = out;
    float* mask = out + (size_t)BIMG * JBOX * CCH * HGT * max_w;

    const int blocks = BIMG * JBOX * HGT;  // 4096
    roi_kernel<<<blocks, 256, 0, stream>>>(img, boxes, res, mask, max_w);
}

// Round 5
// 154.136 us; speedup vs baseline: 1.2667x; 1.2667x over previous
//
#include <hip/hip_runtime.h>

#define HIMG 256
#define WIMG 256
#define CCH  32
#define JBOX 64
#define BIMG 8
#define HGT  8
#define CPW  8   // channels per wave: 256 threads = 4 waves x 8 channels

// Grid: (tiles, B*J*HGT). Block 256 = 4 waves.
// wave wv handles channels [wv*8, wv*8+8); lane = output column within tile.
// This spreads each block's gather dependency chain across 4 waves (R2 had
// it all in wave 0) and turns masked-region waves into pure store+exit.
// All global addressing: wave-uniform SGPR base + per-lane 32-bit offset.
__global__ __launch_bounds__(256) void roi_kernel(
    const float* __restrict__ img,     // (B, C, HIMG, WIMG)
    const float* __restrict__ boxes,   // (B, J, 5)
    float* __restrict__ res,           // (B, J, C, HGT, max_w)
    float* __restrict__ mask,          // (B, J, max_w)
    int max_w)
{
    const int tile = blockIdx.x;
    const int bjh  = blockIdx.y;
    const int h    = bjh & 7;
    const int bj   = bjh >> 3;        // 0..511
    const int b    = bj >> 6;         // J = 64
    const int wv   = threadIdx.x >> 6;   // 0..3 channel group
    const int lane = threadIdx.x & 63;
    const int i    = tile * 64 + lane;

    const float left = boxes[bj * 5 + 0];
    const float top  = boxes[bj * 5 + 1];
    const float bw   = boxes[bj * 5 + 2] - left;
    const float bh   = boxes[bj * 5 + 3] - top;

    // width = int32(bw/bh * 8) with f32 ops + truncation (matches numpy).
    const int   width  = (int)(bw / bh * 8.0f);
    const float each_w = bw / ((float)width - 1.0f);
    const float each_h = bh / 7.0f;

    if (i >= max_w) return;
    const bool in_w = (i < width);

    if (h == 0 && wv == 0) {
        mask[(size_t)bj * max_w + i] = in_w ? 1.0f : 0.0f;
    }

    // res[((bj*C + c)*HGT + h)*max_w + i], this wave's first channel.
    float* resp = res + (((size_t)bj * CCH + wv * CPW) * HGT + h) * (size_t)max_w + i;
    const size_t c_stride = (size_t)HGT * max_w;

    if (!in_w) {
        // Masked region: zeros only, no image reads; wave retires fast.
        #pragma unroll
        for (int c = 0; c < CPW; ++c) {
            resp[(size_t)c * c_stride] = 0.0f;
        }
        return;
    }

    // Separate mul/add roundings so floor() matches numpy bit-exactly.
    const float x = __fadd_rn(__fmul_rn((float)i, each_w), left);
    const float y = __fadd_rn(__fmul_rn((float)h, each_h), top);

    const int xf = (int)floorf(x);
    const int yf = (int)floorf(y);
    const int x0 = min(max(xf,     0), WIMG - 1);
    const int x1 = min(max(xf + 1, 0), WIMG - 1);
    const int y0 = min(max(yf,     0), HIMG - 1);
    const int y1 = min(max(yf + 1, 0), HIMG - 1);

    const float wx1 = (float)x1 - x;
    const float wx0 = x - (float)x0;
    const float wy1 = (float)y1 - y;
    const float wy0 = y - (float)y0;

    const float wa = wx1 * wy1;
    const float wb = wx1 * wy0;
    const float wc = wx0 * wy1;
    const float wd = wx0 * wy0;

    // Wave-uniform image base for this wave's 8 channels.
    const float* im = img + ((size_t)b * CCH + wv * CPW) * (HIMG * WIMG);
    const int o00 = y0 * WIMG + x0;
    const int o10 = y1 * WIMG + x0;
    const int o01 = y0 * WIMG + x1;
    const int o11 = y1 * WIMG + x1;

    // 8 channels x 4 taps = 32 loads in flight per wave.
    #pragma unroll
    for (int c = 0; c < CPW; ++c) {
        const float* imc = im + (size_t)c * (HIMG * WIMG);
        const float va = imc[o00];
        const float vb = imc[o10];
        const float vc = imc[o01];
        const float vd = imc[o11];
        const float val = va * wa + vb * wb + vc * wc + vd * wd;
        resp[(size_t)c * c_stride] = val;
    }
}

extern "C" void kernel_launch(void* const* d_in, const int* in_sizes, int n_in,
                              void* d_out, int out_size, void* d_ws, size_t ws_size,
                              hipStream_t stream) {
    const float* img   = (const float*)d_in[0];
    const float* boxes = (const float*)d_in[1];
    float* out = (float*)d_out;

    const int per_w = BIMG * JBOX * CCH * HGT + BIMG * JBOX;  // 131584
    const int max_w = out_size / per_w;

    float* res  = out;
    float* mask = out + (size_t)BIMG * JBOX * CCH * HGT * max_w;

    const int tiles = (max_w + 63) / 64;                // 3 for max_w=169
    dim3 grid(tiles, BIMG * JBOX * HGT);                // (3, 4096)
    roi_kernel<<<grid, 256, 0, stream>>>(img, boxes, res, mask, max_w);
}

// Round 6
// 153.706 us; speedup vs baseline: 1.2703x; 1.0028x over previous
//
#include <hip/hip_runtime.h>

#define HIMG 256
#define WIMG 256
#define CCH  32
#define JBOX 64
#define BIMG 8
#define HGT  8
#define CPW  8   // channels per wave: 256 threads = 4 waves x 8 channels

// Grid: (tiles, B*J*HGT). Block 256 = 4 waves; wave wv = channels
// [wv*8, wv*8+8), lane = output column within tile.
// R6: issue ALL 32 tap loads into explicit arrays before any use, with
// __launch_bounds__(256,4) granting VGPR headroom (R5's VGPR=32 forced the
// compiler to serialize loads into small vmcnt batches).
__global__ __launch_bounds__(256, 4) void roi_kernel(
    const float* __restrict__ img,     // (B, C, HIMG, WIMG)
    const float* __restrict__ boxes,   // (B, J, 5)
    float* __restrict__ res,           // (B, J, C, HGT, max_w)
    float* __restrict__ mask,          // (B, J, max_w)
    int max_w)
{
    const int tile = blockIdx.x;
    const int bjh  = blockIdx.y;
    const int h    = bjh & 7;
    const int bj   = bjh >> 3;        // 0..511
    const int b    = bj >> 6;         // J = 64
    const int wv   = threadIdx.x >> 6;   // 0..3 channel group
    const int lane = threadIdx.x & 63;
    const int i    = tile * 64 + lane;

    const float left = boxes[bj * 5 + 0];
    const float top  = boxes[bj * 5 + 1];
    const float bw   = boxes[bj * 5 + 2] - left;
    const float bh   = boxes[bj * 5 + 3] - top;

    // width = int32(bw/bh * 8) with f32 ops + truncation (matches numpy).
    const int   width  = (int)(bw / bh * 8.0f);
    const float each_w = bw / ((float)width - 1.0f);
    const float each_h = bh / 7.0f;

    if (i >= max_w) return;
    const bool in_w = (i < width);

    if (h == 0 && wv == 0) {
        mask[(size_t)bj * max_w + i] = in_w ? 1.0f : 0.0f;
    }

    // res[((bj*C + c)*HGT + h)*max_w + i], this wave's first channel.
    float* resp = res + (((size_t)bj * CCH + wv * CPW) * HGT + h) * (size_t)max_w + i;
    const size_t c_stride = (size_t)HGT * max_w;

    if (!in_w) {
        #pragma unroll
        for (int c = 0; c < CPW; ++c) {
            resp[(size_t)c * c_stride] = 0.0f;
        }
        return;
    }

    // Separate mul/add roundings so floor() matches numpy bit-exactly.
    const float x = __fadd_rn(__fmul_rn((float)i, each_w), left);
    const float y = __fadd_rn(__fmul_rn((float)h, each_h), top);

    const int xf = (int)floorf(x);
    const int yf = (int)floorf(y);
    const int x0 = min(max(xf,     0), WIMG - 1);
    const int x1 = min(max(xf + 1, 0), WIMG - 1);
    const int y0 = min(max(yf,     0), HIMG - 1);
    const int y1 = min(max(yf + 1, 0), HIMG - 1);

    const float wx1 = (float)x1 - x;
    const float wx0 = x - (float)x0;
    const float wy1 = (float)y1 - y;
    const float wy0 = y - (float)y0;

    const float wa = wx1 * wy1;
    const float wb = wx1 * wy0;
    const float wc = wx0 * wy1;
    const float wd = wx0 * wy0;

    const float* im = img + ((size_t)b * CCH + wv * CPW) * (HIMG * WIMG);
    const int o00 = y0 * WIMG + x0;
    const int o10 = y1 * WIMG + x0;
    const int o01 = y0 * WIMG + x1;
    const int o11 = y1 * WIMG + x1;

    // Phase 1: issue all 32 loads (no uses in between -> one deep vmcnt batch).
    float va[CPW], vb[CPW], vc[CPW], vd[CPW];
    #pragma unroll
    for (int c = 0; c < CPW; ++c) {
        const float* imc = im + (size_t)c * (HIMG * WIMG);
        va[c] = imc[o00];
        vb[c] = imc[o10];
        vc[c] = imc[o01];
        vd[c] = imc[o11];
    }

    // Phase 2: blend + store.
    #pragma unroll
    for (int c = 0; c < CPW; ++c) {
        const float val = va[c] * wa + vb[c] * wb + vc[c] * wc + vd[c] * wd;
        resp[(size_t)c * c_stride] = val;
    }
}

extern "C" void kernel_launch(void* const* d_in, const int* in_sizes, int n_in,
                              void* d_out, int out_size, void* d_ws, size_t ws_size,
                              hipStream_t stream) {
    const float* img   = (const float*)d_in[0];
    const float* boxes = (const float*)d_in[1];
    float* out = (float*)d_out;

    const int per_w = BIMG * JBOX * CCH * HGT + BIMG * JBOX;  // 131584
    const int max_w = out_size / per_w;

    float* res  = out;
    float* mask = out + (size_t)BIMG * JBOX * CCH * HGT * max_w;

    const int tiles = (max_w + 63) / 64;                // 3 for max_w=169
    dim3 grid(tiles, BIMG * JBOX * HGT);                // (3, 4096)
    roi_kernel<<<grid, 256, 0, stream>>>(img, boxes, res, mask, max_w);
}